// Round 6
// baseline (497.618 us; speedup 1.0000x reference)
//
#include <hip/hip_runtime.h>
#include <hip/hip_bf16.h>
#include <math.h>

#define Hh 4
#define Bb 32
#define Tt 1000
#define TP 1024
#define EPROJS_ 1024
#define DUNITS_ 1024
#define DKd 512
#define DVd 512
#define CC 100
#define KPAD 256
#define SCALING 0.04419417382415922f  // 1/sqrt(512)

typedef __attribute__((ext_vector_type(8))) short short8;
typedef __attribute__((ext_vector_type(4))) float floatx4;

__device__ __forceinline__ void async16(const void* g, void* l) {
    __builtin_amdgcn_global_load_lds(
        (const __attribute__((address_space(1))) unsigned int*)g,
        (__attribute__((address_space(3))) unsigned int*)l, 16, 0, 0);
}

// fast tanh: 1 transcendental + 1 rcp instead of libm tanhf
__device__ __forceinline__ float fast_tanh(float x) {
    float xc = fminf(fmaxf(x, -10.f), 10.f);
    float t = __expf(2.f * xc);                 // v_exp_f32 path
    return (t - 1.f) * __builtin_amdgcn_rcpf(t + 1.f);
}

// ---- fused prep: wkt (512) + ww (1024) + q (256) + enc_cvt (2048 grid-stride)
__global__ __launch_bounds__(256) void prep_kernel(
    const float* __restrict__ Wk, unsigned short* __restrict__ Wkt,
    const float* __restrict__ w0, const float* __restrict__ w1,
    const float* __restrict__ w2, const float* __restrict__ w3,
    const float* __restrict__ Watt, __hip_bfloat16* __restrict__ WWt,
    const float* __restrict__ dec_z, const float* __restrict__ Wq,
    float* __restrict__ q_buf,
    const float* __restrict__ enc, unsigned short* __restrict__ enc16)
{
    __shared__ float shbuf[64 * 65];
    const int bid = blockIdx.x;
    const int tid = threadIdx.x;
    if (bid < 512) {
        // ---- Wkt[h][e][d] = bf16(Wk[h][d][e]) — 64x64 transpose ----
        int et = bid & 7, dt = (bid >> 3) & 15, h = bid >> 7;
        float (*tile)[65] = (float(*)[65])shbuf;
        int r = tid >> 4, c4 = tid & 15;
        const float* src = Wk + ((size_t)(h * DUNITS_ + dt * 64)) * DKd + et * 64;
#pragma unroll
        for (int rr = 0; rr < 4; ++rr) {
            int row = r + rr * 16;
            *(float4*)&tile[row][c4 * 4] = *(const float4*)(src + (size_t)row * DKd + c4 * 4);
        }
        __syncthreads();
        unsigned short* dst = Wkt + ((size_t)(h * DKd + et * 64)) * EPROJS_ + dt * 64;
#pragma unroll
        for (int rr = 0; rr < 4; ++rr) {
            int el = r + rr * 16;
            union { __hip_bfloat162 h2[2]; uint2 u; } u;
            u.h2[0] = __float22bfloat162_rn(make_float2(tile[c4 * 4 + 0][el], tile[c4 * 4 + 1][el]));
            u.h2[1] = __float22bfloat162_rn(make_float2(tile[c4 * 4 + 2][el], tile[c4 * 4 + 3][el]));
            *(uint2*)(dst + (size_t)el * EPROJS_ + c4 * 4) = u.u;
        }
    } else if (bid < 1536) {
        // ---- WWt[h][e][k] = bf16(sum_c cw_h[c,k]*Watt[h,c,e]) ----
        int b2 = bid - 512;
        int k = b2 & 255, h = b2 >> 8;
        int f = 25 * (h + 1), Kh = 2 * f + 1;
        const float* cw = (h == 0) ? w0 : (h == 1) ? w1 : (h == 2) ? w2 : w3;
        int e = tid;
        float acc0 = 0.f, acc1 = 0.f;
        if (k < Kh) {
            for (int c = 0; c < CC; ++c) {
                float wv = cw[c * Kh + k];
                acc0 += wv * Watt[(h * CC + c) * DKd + e];
                acc1 += wv * Watt[(h * CC + c) * DKd + e + 256];
            }
        }
        WWt[((size_t)(h * DKd + e)) * KPAD + k] = __float2bfloat16(acc0);
        WWt[((size_t)(h * DKd + e + 256)) * KPAD + k] = __float2bfloat16(acc1);
    } else if (bid < 1792) {
        // ---- q[h,b,e] += dec_z[b,d0:d0+64] . Wq[h,d0:d0+64,e] ----
        int b3 = bid - 1536;
        int et = b3 & 3, kc = (b3 >> 2) & 15, h = b3 >> 6;
        int d0 = kc * 64;
        float (*zs)[64] = (float(*)[64])shbuf;
        {
            int b = tid >> 3, dc = (tid & 7) * 8;
            const float* p = dec_z + (size_t)b * DUNITS_ + d0 + dc;
            *(float4*)&zs[b][dc] = *(const float4*)p;
            *(float4*)&zs[b][dc + 4] = *(const float4*)(p + 4);
        }
        __syncthreads();
        int e = et * 128 + (tid & 127);
        int dl0 = (tid >> 7) * 32;
        float wq[32];
#pragma unroll
        for (int dl = 0; dl < 32; ++dl)
            wq[dl] = Wq[((size_t)(h * DUNITS_ + d0 + dl0 + dl)) * DKd + e];
#pragma unroll
        for (int b = 0; b < 32; ++b) {
            float s = 0.f;
#pragma unroll
            for (int dl = 0; dl < 32; ++dl) s += zs[b][dl0 + dl] * wq[dl];
            atomicAdd(&q_buf[(h * Bb + b) * DKd + e], s);
        }
    } else {
        // ---- enc16[b][t][d] = bf16(enc[b][t][d]) — grid-stride ----
        const int total = Bb * Tt * (EPROJS_ / 4);
        const int nblk = 2048;
        for (int idx = (bid - 1792) * 256 + tid; idx < total; idx += nblk * 256) {
            int d4 = idx & 255;
            int bt = idx >> 8;
            int b = bt / Tt, t = bt - b * Tt;
            float4 v = *(const float4*)(enc + (size_t)idx * 4);
            union { __hip_bfloat162 h2[2]; uint2 u; } u;
            u.h2[0] = __float22bfloat162_rn(make_float2(v.x, v.y));
            u.h2[1] = __float22bfloat162_rn(make_float2(v.z, v.w));
            *(uint2*)(enc16 + ((size_t)(b * TP + t)) * EPROJS_ + d4 * 4) = u.u;
        }
    }
}

// ---------------- e[h,b,t]: MFMA bf16 GEMM + fused tanh-dot epilogue -----------
// v7: m201 geometry + schedule. 256x256 tile, 8 waves (512 thr, 2x4 grid,
// 128x64 wave-tile -> reads:MFMA = 0.375), BK=64 dbuf. Per K-tile 4 phases:
// {ds_read subtile; 2 async16 of next tile; barrier; lgkmcnt(0); setprio(1);
// 16 MFMA; setprio(0); barrier}, drain vmcnt(0) once at phase 3 (loads issued
// >=1 phase earlier). XCD map: b-grouped (v5 - best FETCH/locality).
__global__ __launch_bounds__(512, 2) void e_kernel(
    const unsigned short* __restrict__ enc16, const unsigned short* __restrict__ Wkt,
    const float* __restrict__ att_prev, const __hip_bfloat16* __restrict__ WWt,
    const float* __restrict__ q_buf, const float* __restrict__ bq,
    const float* __restrict__ g_w, float* __restrict__ e_buf)
{
    const int lin = blockIdx.x;                       // 1024 blocks
    const int xcd = lin & 7, pos = lin >> 3;          // pos 0..127
    const int b = (pos >> 5) * 8 + xcd;               // 4 batch-groups per XCD
    const int rem = pos & 31;
    const int h = rem >> 3;
    const int by = (rem >> 1) & 3;                    // t-tile
    const int bx = rem & 1;                           // e-tile
    const int t0 = by * 256, e0 = bx * 256;
    const int tid = threadIdx.x;
    const int lane = tid & 63, w = tid >> 6;          // 8 waves
    const int wr = w >> 2, wc = w & 3;                // 2x4: wave tile 128t x 64e
    const int m = lane & 15, quad = lane >> 4;
    const int srow = tid >> 3;                        // 0..63
    const int ko = (((tid & 7) ^ (srow & 7))) * 8;    // swizzled k-offset (elems)
    const int sw = m & 7;                             // fragment-read swizzle

    __shared__ __align__(16) short As[2][256 * 64];   // 2 x 32 KB
    __shared__ __align__(16) short Bs[2][256 * 64];   // 2 x 32 KB

    floatx4 acc[8][4];
#pragma unroll
    for (int i = 0; i < 8; ++i)
#pragma unroll
        for (int j = 0; j < 4; ++j) acc[i][j] = (floatx4){0.f, 0.f, 0.f, 0.f};

    const unsigned short* WkB = Wkt + ((size_t)(h * DKd + e0)) * EPROJS_;
    const unsigned short* encB = enc16 + ((size_t)(b * TP + t0)) * EPROJS_;

    // one 16B load into A and one into B, row-round `it` (0..3), chunk, buffer
    auto stage2 = [&](int chunk, int bi, int it) {
        const int d0 = chunk * 64;
        char* ad = (char*)As[bi] + (tid & ~63) * 16;
        char* bd = (char*)Bs[bi] + (tid & ~63) * 16;
        int r2 = it * 64 + srow;
        async16(encB + (size_t)r2 * EPROJS_ + d0 + ko, ad + it * 8192);
        async16(WkB + (size_t)r2 * EPROJS_ + d0 + ko, bd + it * 8192);
    };

    // ---- prologue: fully stage chunk 0 into buffer 0 ----
#pragma unroll
    for (int it = 0; it < 4; ++it) stage2(0, 0, it);
    asm volatile("s_waitcnt vmcnt(0)" ::: "memory");
    __builtin_amdgcn_s_barrier();

    // ---- phase 1: K=1024, 16 chunks, 4 sub-phases each ----
    for (int ch = 0; ch < 16; ++ch) {
        const int cur = ch & 1;
        short8 bf[4];
#pragma unroll
        for (int ph = 0; ph < 4; ++ph) {
            const int ks = ph >> 1, ih = ph & 1;
            const int col = (((ks << 2) + quad) ^ sw) * 8;
            short8 af[4];
#pragma unroll
            for (int i = 0; i < 4; ++i)
                af[i] = *(const short8*)&As[cur][(wr * 128 + ih * 64 + i * 16 + m) * 64 + col];
            if (ih == 0) {
#pragma unroll
                for (int j = 0; j < 4; ++j)
                    bf[j] = *(const short8*)&Bs[cur][(wc * 64 + j * 16 + m) * 64 + col];
            }
            if (ch < 15) stage2(ch + 1, cur ^ 1, ph);   // 2 loads/phase, 8/chunk
            __builtin_amdgcn_sched_barrier(0);
            __builtin_amdgcn_s_barrier();               // convoy waves
            asm volatile("s_waitcnt lgkmcnt(0)" ::: "memory");
            __builtin_amdgcn_sched_barrier(0);          // rule #18 fence
            __builtin_amdgcn_s_setprio(1);
#pragma unroll
            for (int i = 0; i < 4; ++i)
#pragma unroll
                for (int j = 0; j < 4; ++j)
                    acc[ih * 4 + i][j] = __builtin_amdgcn_mfma_f32_16x16x32_bf16(
                        af[i], bf[j], acc[ih * 4 + i][j], 0, 0, 0);
            __builtin_amdgcn_s_setprio(0);
            __builtin_amdgcn_sched_barrier(0);
            if (ph == 3 && ch < 15)                     // next tile fully landed
                asm volatile("s_waitcnt vmcnt(0)" ::: "memory");
            __builtin_amdgcn_s_barrier();               // phase done
        }
    }

    // ---- phase 2: banded location term over k, BK=64 (uses buffer 0) ----
    const int f = 25 * (h + 1);
    const int Kh = 2 * f + 1;
    const int nch2 = (Kh + 63) >> 6;
    const float* ab = att_prev + (size_t)(h * Bb + b) * Tt;
    const __hip_bfloat16* WWB = WWt + ((size_t)(h * DKd + e0)) * KPAD;
    char* BsDst0 = (char*)Bs[0] + (tid & ~63) * 16;
    for (int ch = 0; ch < nch2; ++ch) {
        int k0 = ch * 64;
        int ar = tid >> 1, half = tid & 1;            // ar 0..255
        int sbase = t0 + ar - f + k0 + half * 32;
        float v[32];
#pragma unroll
        for (int j2 = 0; j2 < 32; ++j2) {
            int s = sbase + j2;
            v[j2] = (s >= 0 && s < Tt) ? ab[s] : 0.f;
        }
        __syncthreads();
#pragma unroll
        for (int it = 0; it < 4; ++it) {
            int r2 = it * 64 + srow;
            async16(WWB + (size_t)r2 * KPAD + k0 + ko, BsDst0 + it * 8192);
        }
        union { short8 s[4]; __hip_bfloat162 hh[16]; } u;
#pragma unroll
        for (int j2 = 0; j2 < 16; ++j2)
            u.hh[j2] = __float22bfloat162_rn(make_float2(v[2 * j2], v[2 * j2 + 1]));
#pragma unroll
        for (int jj = 0; jj < 4; ++jj) {
            int phys = (half * 4 + jj) ^ (ar & 7);
            *(short8*)&As[0][ar * 64 + phys * 8] = u.s[jj];
        }
        __syncthreads();
#pragma unroll
        for (int ks = 0; ks < 2; ++ks) {
            short8 af[8], bf2[4];
#pragma unroll
            for (int i = 0; i < 8; ++i)
                af[i] = *(const short8*)&As[0][(wr * 128 + i * 16 + m) * 64 + (((ks << 2) + quad) ^ sw) * 8];
#pragma unroll
            for (int j = 0; j < 4; ++j)
                bf2[j] = *(const short8*)&Bs[0][(wc * 64 + j * 16 + m) * 64 + (((ks << 2) + quad) ^ sw) * 8];
            __builtin_amdgcn_s_setprio(1);
#pragma unroll
            for (int i = 0; i < 8; ++i)
#pragma unroll
                for (int j = 0; j < 4; ++j)
                    acc[i][j] = __builtin_amdgcn_mfma_f32_16x16x32_bf16(
                        af[i], bf2[j], acc[i][j], 0, 0, 0);
            __builtin_amdgcn_s_setprio(0);
        }
    }

    // ---- epilogue: +q+bq, tanh, *g_w, reduce 16 cols/quad, atomicAdd ----------
    const float* qrow = q_buf + (size_t)(h * Bb + b) * DKd;
    const float* bqrow = bq + h * DKd;
    const float* gwrow = g_w + h * DKd;
    float qv[4], gw[4];
#pragma unroll
    for (int j = 0; j < 4; ++j) {
        int e = e0 + wc * 64 + j * 16 + m;
        qv[j] = qrow[e] + bqrow[e];
        gw[j] = gwrow[e];
    }
    float* erow = e_buf + (size_t)(h * Bb + b) * Tt;
#pragma unroll
    for (int i = 0; i < 8; ++i) {
#pragma unroll
        for (int reg = 0; reg < 4; ++reg) {
            float s = 0.f;
#pragma unroll
            for (int j = 0; j < 4; ++j)
                s += fast_tanh(acc[i][j][reg] + qv[j]) * gw[j];
            s += __shfl_xor(s, 1);
            s += __shfl_xor(s, 2);
            s += __shfl_xor(s, 4);
            s += __shfl_xor(s, 8);
            int t = t0 + wr * 128 + i * 16 + quad * 4 + reg;
            if (m == 0 && t < Tt)
                atomicAdd(&erow[t], s);
        }
    }
}

// ---------------- w = softmax(scaling * e) over T ------------------------------
__global__ __launch_bounds__(256) void softmax_kernel(
    const float* __restrict__ e_buf, float* __restrict__ wout)
{
    int rowid = blockIdx.x;
    const float* x = e_buf + rowid * Tt;
    float* y = wout + rowid * Tt;
    int tid = threadIdx.x;
    float v[4];
    float mx = -1e30f;
#pragma unroll
    for (int k = 0; k < 4; ++k) {
        int t = tid + k * 256;
        v[k] = (t < Tt) ? x[t] * SCALING : -1e30f;
        mx = fmaxf(mx, v[k]);
    }
    for (int off = 32; off >= 1; off >>= 1) mx = fmaxf(mx, __shfl_xor(mx, off));
    __shared__ float sm[4];
    __shared__ float ss[4];
    int wave = tid >> 6;
    if ((tid & 63) == 0) sm[wave] = mx;
    __syncthreads();
    mx = fmaxf(fmaxf(sm[0], sm[1]), fmaxf(sm[2], sm[3]));
    float s = 0.f;
#pragma unroll
    for (int k = 0; k < 4; ++k) {
        int t = tid + k * 256;
        v[k] = (t < Tt) ? __expf(v[k] - mx) : 0.f;
        s += v[k];
    }
    for (int off = 32; off >= 1; off >>= 1) s += __shfl_xor(s, off);
    if ((tid & 63) == 0) ss[wave] = s;
    __syncthreads();
    s = ss[0] + ss[1] + ss[2] + ss[3];
    float inv = 1.0f / s;
#pragma unroll
    for (int k = 0; k < 4; ++k) {
        int t = tid + k * 256;
        if (t < Tt) y[t] = v[k] * inv;
    }
}

// ---------------- ctx[h,b,d] += sum_{t in tile} w[h,b,t] * enc16[b,t,d] -------
__global__ __launch_bounds__(256) void ctx_kernel(
    const float* __restrict__ wout, const unsigned short* __restrict__ enc16,
    float* __restrict__ ctx)
{
    int dch = blockIdx.x;    // 0..7 : 128-d chunk
    int b = blockIdx.y;      // 0..31
    int tq = blockIdx.z;     // 0..3 : 250-t chunk
    int t0 = tq * 250;
    int tid = threadIdx.x;
    __shared__ float wl[4][252];
    __shared__ float red[8 * 4 * 128];
    for (int i = tid; i < 1000; i += 256) {
        int h = i / 250, tl = i - h * 250;
        wl[h][tl] = wout[(h * Bb + b) * Tt + t0 + tl];
    }
    __syncthreads();
    int g = tid >> 5, c = tid & 31;
    int d0 = dch * 128;
    float4 a[4];
#pragma unroll
    for (int h = 0; h < 4; ++h) a[h] = make_float4(0.f, 0.f, 0.f, 0.f);
    const unsigned short* encB = enc16 + (size_t)b * TP * EPROJS_ + d0 + c * 4;
    for (int t = t0 + g; t < t0 + 250; t += 8) {
        uint2 raw = *(const uint2*)(encB + (size_t)t * EPROJS_);
        float x0 = __uint_as_float(raw.x << 16);
        float x1 = __uint_as_float(raw.x & 0xffff0000u);
        float x2 = __uint_as_float(raw.y << 16);
        float x3 = __uint_as_float(raw.y & 0xffff0000u);
#pragma unroll
        for (int h = 0; h < 4; ++h) {
            float wv = wl[h][t - t0];
            a[h].x += wv * x0; a[h].y += wv * x1;
            a[h].z += wv * x2; a[h].w += wv * x3;
        }
    }
#pragma unroll
    for (int h = 0; h < 4; ++h)
        *(float4*)&red[((g * 4 + h) << 7) + c * 4] = a[h];
    __syncthreads();
    for (int i = tid; i < 512; i += 256) {
        int h = i >> 7, dd = i & 127;
        float ssum = 0.f;
#pragma unroll
        for (int g2 = 0; g2 < 8; ++g2) ssum += red[((g2 * 4 + h) << 7) + dd];
        atomicAdd(&ctx[(h * Bb + b) * EPROJS_ + d0 + dd], ssum);
    }
}

// ---------------- c[h,b,e] += ctx[h,b,d0:d0+64] . Wv[h,d0:d0+64,e] ------------
__global__ __launch_bounds__(256) void c_kernel(
    const float* __restrict__ ctx, const float* __restrict__ Wv,
    float* __restrict__ c_buf)
{
    int et = blockIdx.x, kc = blockIdx.y, h = blockIdx.z;
    int d0 = kc * 64;
    __shared__ float zs[32][64];
    int tid = threadIdx.x;
    {
        int b = tid >> 3, dc = (tid & 7) * 8;
        const float* p = ctx + ((size_t)(h * Bb + b)) * EPROJS_ + d0 + dc;
        *(float4*)&zs[b][dc] = *(const float4*)p;
        *(float4*)&zs[b][dc + 4] = *(const float4*)(p + 4);
    }
    __syncthreads();
    int e = et * 128 + (tid & 127);
    int dl0 = (tid >> 7) * 32;
    float wv[32];
#pragma unroll
    for (int dl = 0; dl < 32; ++dl)
        wv[dl] = Wv[((size_t)(h * EPROJS_ + d0 + dl0 + dl)) * DVd + e];
#pragma unroll
    for (int b = 0; b < 32; ++b) {
        float s = 0.f;
#pragma unroll
        for (int dl = 0; dl < 32; ++dl) s += zs[b][dl0 + dl] * wv[dl];
        atomicAdd(&c_buf[(h * Bb + b) * DVd + e], s);
    }
}

// ---------------- out[b,o] += c[b,k0:k0+64] . Wo[k0:k0+64,o] ------------------
__global__ __launch_bounds__(256) void out_kernel(
    const float* __restrict__ c_buf, const float* __restrict__ Wo,
    float* __restrict__ outp)
{
    int ot = blockIdx.x;  // 0..7 : 128-o tile
    int kc = blockIdx.y;  // 0..31: 64-k chunk
    int k0 = kc * 64, o0 = ot * 128;
    __shared__ float cs[32][64];
    int tid = threadIdx.x;
    {
        int b = tid >> 3, k8 = (tid & 7) * 8;
        int h = k0 >> 9;
        const float* p = c_buf + ((size_t)(h * Bb + b)) * DVd + (k0 & 511) + k8;
        *(float4*)&cs[b][k8] = *(const float4*)p;
        *(float4*)&cs[b][k8 + 4] = *(const float4*)(p + 4);
    }
    __syncthreads();
    int o = o0 + (tid & 127);
    int kl0 = (tid >> 7) * 32;
    float wo[32];
#pragma unroll
    for (int kl = 0; kl < 32; ++kl)
        wo[kl] = Wo[((size_t)(k0 + kl0 + kl)) * EPROJS_ + o];
#pragma unroll
    for (int b = 0; b < 32; ++b) {
        float s = 0.f;
#pragma unroll
        for (int kl = 0; kl < 32; ++kl) s += cs[b][kl0 + kl] * wo[kl];
        atomicAdd(&outp[b * EPROJS_ + o], s);
    }
}

extern "C" void kernel_launch(void* const* d_in, const int* in_sizes, int n_in,
                              void* d_out, int out_size, void* d_ws, size_t ws_size,
                              hipStream_t stream) {
    const float* enc     = (const float*)d_in[0];
    const float* dec_z   = (const float*)d_in[2];
    const float* att_prev= (const float*)d_in[3];
    const float* Wq      = (const float*)d_in[4];
    const float* bq      = (const float*)d_in[5];
    const float* Wk      = (const float*)d_in[6];
    const float* Wv      = (const float*)d_in[7];
    const float* g_w     = (const float*)d_in[8];
    const float* Watt    = (const float*)d_in[10];
    const float* Wo      = (const float*)d_in[11];
    const float* cw0     = (const float*)d_in[12];
    const float* cw1     = (const float*)d_in[13];
    const float* cw2     = (const float*)d_in[14];
    const float* cw3     = (const float*)d_in[15];

    float* ws    = (float*)d_ws;
    float* q_buf = ws;                          // 65536 f
    float* e_buf = ws + 65536;                  // 128000 f
    float* c_buf = ws + 193536;                 // 65536 f
    float* ctx   = ws + 259072;                 // 131072 f   (zeroed through here)
    unsigned short* enc16 = (unsigned short*)(ws + 390144);   // 32*1024*1024 bf16
    unsigned short* Wkt   = (unsigned short*)(ws + 17167360); // 4*512*1024 bf16
    __hip_bfloat16* WWt   = (__hip_bfloat16*)(ws + 18215936); // 4*512*256 bf16
    float* outp  = (float*)d_out;               // 32768 f
    float* wout  = outp + 32768;                // 128000 f

    // zero atomic-accumulated buffers: q, e, c, ctx, out
    hipMemsetAsync(ws, 0, (size_t)390144 * sizeof(float), stream);
    hipMemsetAsync(d_out, 0, (size_t)32768 * sizeof(float), stream);

    prep_kernel<<<3840, 256, 0, stream>>>(Wk, Wkt, cw0, cw1, cw2, cw3, Watt, WWt,
                                          dec_z, Wq, q_buf, enc, enc16);
    e_kernel<<<1024, 512, 0, stream>>>(enc16, Wkt, att_prev, WWt,
                                       q_buf, bq, g_w, e_buf);
    softmax_kernel<<<128, 256, 0, stream>>>(e_buf, wout);
    ctx_kernel<<<dim3(8, 32, 4), 256, 0, stream>>>(wout, enc16, ctx);
    c_kernel<<<dim3(4, 16, 4), 256, 0, stream>>>(ctx, Wv, c_buf);
    out_kernel<<<dim3(8, 32), 256, 0, stream>>>(c_buf, Wo, outp);
}

// Round 7
// 475.903 us; speedup vs baseline: 1.0456x; 1.0456x over previous
//
#include <hip/hip_runtime.h>
#include <hip/hip_bf16.h>
#include <math.h>

#define Hh 4
#define Bb 32
#define Tt 1000
#define TP 1024
#define EPROJS_ 1024
#define DUNITS_ 1024
#define DKd 512
#define DVd 512
#define CC 100
#define KPAD 256
#define SCALING 0.04419417382415922f  // 1/sqrt(512)

typedef __attribute__((ext_vector_type(8))) short short8;
typedef __attribute__((ext_vector_type(4))) float floatx4;

__device__ __forceinline__ void async16(const void* g, void* l) {
    __builtin_amdgcn_global_load_lds(
        (const __attribute__((address_space(1))) unsigned int*)g,
        (__attribute__((address_space(3))) unsigned int*)l, 16, 0, 0);
}

// fast tanh: 1 transcendental + 1 rcp instead of libm tanhf
__device__ __forceinline__ float fast_tanh(float x) {
    float xc = fminf(fmaxf(x, -10.f), 10.f);
    float t = __expf(2.f * xc);                 // v_exp_f32 path
    return (t - 1.f) * __builtin_amdgcn_rcpf(t + 1.f);
}

// ---- fused prep: wkt (512) + ww (1024) + q (256) + enc_cvt (2048 grid-stride)
__global__ __launch_bounds__(256) void prep_kernel(
    const float* __restrict__ Wk, unsigned short* __restrict__ Wkt,
    const float* __restrict__ w0, const float* __restrict__ w1,
    const float* __restrict__ w2, const float* __restrict__ w3,
    const float* __restrict__ Watt, __hip_bfloat16* __restrict__ WWt,
    const float* __restrict__ dec_z, const float* __restrict__ Wq,
    float* __restrict__ q_buf,
    const float* __restrict__ enc, unsigned short* __restrict__ enc16)
{
    __shared__ float shbuf[64 * 65];
    const int bid = blockIdx.x;
    const int tid = threadIdx.x;
    if (bid < 512) {
        // ---- Wkt[h][e][d] = bf16(Wk[h][d][e]) — 64x64 transpose ----
        int et = bid & 7, dt = (bid >> 3) & 15, h = bid >> 7;
        float (*tile)[65] = (float(*)[65])shbuf;
        int r = tid >> 4, c4 = tid & 15;
        const float* src = Wk + ((size_t)(h * DUNITS_ + dt * 64)) * DKd + et * 64;
#pragma unroll
        for (int rr = 0; rr < 4; ++rr) {
            int row = r + rr * 16;
            *(float4*)&tile[row][c4 * 4] = *(const float4*)(src + (size_t)row * DKd + c4 * 4);
        }
        __syncthreads();
        unsigned short* dst = Wkt + ((size_t)(h * DKd + et * 64)) * EPROJS_ + dt * 64;
#pragma unroll
        for (int rr = 0; rr < 4; ++rr) {
            int el = r + rr * 16;
            union { __hip_bfloat162 h2[2]; uint2 u; } u;
            u.h2[0] = __float22bfloat162_rn(make_float2(tile[c4 * 4 + 0][el], tile[c4 * 4 + 1][el]));
            u.h2[1] = __float22bfloat162_rn(make_float2(tile[c4 * 4 + 2][el], tile[c4 * 4 + 3][el]));
            *(uint2*)(dst + (size_t)el * EPROJS_ + c4 * 4) = u.u;
        }
    } else if (bid < 1536) {
        // ---- WWt[h][e][k] = bf16(sum_c cw_h[c,k]*Watt[h,c,e]) ----
        int b2 = bid - 512;
        int k = b2 & 255, h = b2 >> 8;
        int f = 25 * (h + 1), Kh = 2 * f + 1;
        const float* cw = (h == 0) ? w0 : (h == 1) ? w1 : (h == 2) ? w2 : w3;
        int e = tid;
        float acc0 = 0.f, acc1 = 0.f;
        if (k < Kh) {
            for (int c = 0; c < CC; ++c) {
                float wv = cw[c * Kh + k];
                acc0 += wv * Watt[(h * CC + c) * DKd + e];
                acc1 += wv * Watt[(h * CC + c) * DKd + e + 256];
            }
        }
        WWt[((size_t)(h * DKd + e)) * KPAD + k] = __float2bfloat16(acc0);
        WWt[((size_t)(h * DKd + e + 256)) * KPAD + k] = __float2bfloat16(acc1);
    } else if (bid < 1792) {
        // ---- q[h,b,e] += dec_z[b,d0:d0+64] . Wq[h,d0:d0+64,e] ----
        int b3 = bid - 1536;
        int et = b3 & 3, kc = (b3 >> 2) & 15, h = b3 >> 6;
        int d0 = kc * 64;
        float (*zs)[64] = (float(*)[64])shbuf;
        {
            int b = tid >> 3, dc = (tid & 7) * 8;
            const float* p = dec_z + (size_t)b * DUNITS_ + d0 + dc;
            *(float4*)&zs[b][dc] = *(const float4*)p;
            *(float4*)&zs[b][dc + 4] = *(const float4*)(p + 4);
        }
        __syncthreads();
        int e = et * 128 + (tid & 127);
        int dl0 = (tid >> 7) * 32;
        float wq[32];
#pragma unroll
        for (int dl = 0; dl < 32; ++dl)
            wq[dl] = Wq[((size_t)(h * DUNITS_ + d0 + dl0 + dl)) * DKd + e];
#pragma unroll
        for (int b = 0; b < 32; ++b) {
            float s = 0.f;
#pragma unroll
            for (int dl = 0; dl < 32; ++dl) s += zs[b][dl0 + dl] * wq[dl];
            atomicAdd(&q_buf[(h * Bb + b) * DKd + e], s);
        }
    } else {
        // ---- enc16[b][t][d] = bf16(enc[b][t][d]) — grid-stride ----
        const int total = Bb * Tt * (EPROJS_ / 4);
        const int nblk = 2048;
        for (int idx = (bid - 1792) * 256 + tid; idx < total; idx += nblk * 256) {
            int d4 = idx & 255;
            int bt = idx >> 8;
            int b = bt / Tt, t = bt - b * Tt;
            float4 v = *(const float4*)(enc + (size_t)idx * 4);
            union { __hip_bfloat162 h2[2]; uint2 u; } u;
            u.h2[0] = __float22bfloat162_rn(make_float2(v.x, v.y));
            u.h2[1] = __float22bfloat162_rn(make_float2(v.z, v.w));
            *(uint2*)(enc16 + ((size_t)(b * TP + t)) * EPROJS_ + d4 * 4) = u.u;
        }
    }
}

// ---------------- e[h,b,t]: MFMA bf16 GEMM + fused tanh-dot epilogue -----------
// v8: v5 geometry (256x256, 16 waves, BK=64, dbuf, vmcnt-counted prefetch)
// with a SINGLE barrier per K-chunk: {vmcnt(0 own); barrier; stage(ch+1 ->
// other buf); ds_read+MFMA(cur)}. Safe because: (RAW) every wave vmcnt-retires
// its own stage pre-barrier, so post-barrier all data landed; (WAR) reads of
// the buffer being overwritten completed before their wave's barrier arrival
// (compiler lgkmcnt precedes MFMA use). Halves barrier count vs v5 and gives
// the stage a full compute phase to land.
__global__ __launch_bounds__(1024) void e_kernel(
    const unsigned short* __restrict__ enc16, const unsigned short* __restrict__ Wkt,
    const float* __restrict__ att_prev, const __hip_bfloat16* __restrict__ WWt,
    const float* __restrict__ q_buf, const float* __restrict__ bq,
    const float* __restrict__ g_w, float* __restrict__ e_buf)
{
    const int lin = blockIdx.x;                       // 1024 blocks
    const int xcd = lin & 7, pos = lin >> 3;          // pos 0..127
    const int b = (pos >> 5) * 8 + xcd;               // 4 batch-groups per XCD
    const int rem = pos & 31;
    const int h = rem >> 3;
    const int by = (rem >> 1) & 3;                    // t-tile
    const int bx = rem & 1;                           // e-tile
    const int t0 = by * 256, e0 = bx * 256;
    const int tid = threadIdx.x;
    const int lane = tid & 63, w = tid >> 6;          // 16 waves
    const int wr = w >> 2, wc = w & 3;                // 4x4: wave tile 64t x 64e
    const int m = lane & 15, quad = lane >> 4;
    const int srow = tid >> 3;                        // 0..127
    const int ko = (((tid & 7) ^ (srow & 7))) * 8;    // swizzled k-offset (elems)
    const int sw = m & 7;                             // fragment-read swizzle

    __shared__ __align__(16) short As[2][256 * 64];   // 2 x 32 KB
    __shared__ __align__(16) short Bs[2][256 * 64];   // 2 x 32 KB

    floatx4 acc[4][4];
#pragma unroll
    for (int i = 0; i < 4; ++i)
#pragma unroll
        for (int j = 0; j < 4; ++j) acc[i][j] = (floatx4){0.f, 0.f, 0.f, 0.f};

    const unsigned short* WkB = Wkt + ((size_t)(h * DKd + e0)) * EPROJS_;
    const unsigned short* encB = enc16 + ((size_t)(b * TP + t0)) * EPROJS_;

    auto stage1 = [&](int chunk, int bi) {
        const int d0 = chunk * 64;
        char* ad = (char*)As[bi] + (tid & ~63) * 16;   // wave-uniform base
        char* bd = (char*)Bs[bi] + (tid & ~63) * 16;
#pragma unroll
        for (int it = 0; it < 2; ++it) {
            int r2 = it * 128 + srow;
            async16(encB + (size_t)r2 * EPROJS_ + d0 + ko, ad + it * 16384);
            async16(WkB + (size_t)r2 * EPROJS_ + d0 + ko, bd + it * 16384);
        }
    };

    // ---- phase 1: K=1024, BK=64, dbuf, ONE barrier per chunk ----
    stage1(0, 0);
    for (int ch = 0; ch < 16; ++ch) {
        const int cur = ch & 1;
        asm volatile("s_waitcnt vmcnt(0)" ::: "memory");  // own stage landed
        __builtin_amdgcn_sched_barrier(0);
        __builtin_amdgcn_s_barrier();        // all stages landed; prev reads done
        __builtin_amdgcn_sched_barrier(0);
        if (ch < 15) stage1(ch + 1, cur ^ 1);   // overwrite-safe post-barrier
        __builtin_amdgcn_sched_barrier(0);      // pin stage issue before compute
#pragma unroll
        for (int ks = 0; ks < 2; ++ks) {
            short8 af[4], bf[4];
#pragma unroll
            for (int i = 0; i < 4; ++i)
                af[i] = *(const short8*)&As[cur][(wr * 64 + i * 16 + m) * 64 + (((ks << 2) + quad) ^ sw) * 8];
#pragma unroll
            for (int j = 0; j < 4; ++j)
                bf[j] = *(const short8*)&Bs[cur][(wc * 64 + j * 16 + m) * 64 + (((ks << 2) + quad) ^ sw) * 8];
#pragma unroll
            for (int i = 0; i < 4; ++i)
#pragma unroll
                for (int j = 0; j < 4; ++j)
                    acc[i][j] = __builtin_amdgcn_mfma_f32_16x16x32_bf16(
                        af[i], bf[j], acc[i][j], 0, 0, 0);
        }
    }

    // ---- phase 2: banded location term over k, BK=64 (uses buffer 0) ----
    const int f = 25 * (h + 1);
    const int Kh = 2 * f + 1;
    const int nch2 = (Kh + 63) >> 6;
    const float* ab = att_prev + (size_t)(h * Bb + b) * Tt;
    const __hip_bfloat16* WWB = WWt + ((size_t)(h * DKd + e0)) * KPAD;
    char* BsDst0 = (char*)Bs[0] + (tid & ~63) * 16;
    for (int ch = 0; ch < nch2; ++ch) {
        int k0 = ch * 64;
        int ar = tid >> 2, q4 = tid & 3;              // ar 0..255, 16-elem quarter
        int sbase = t0 + ar - f + k0 + q4 * 16;
        float v[16];
#pragma unroll
        for (int j2 = 0; j2 < 16; ++j2) {
            int s = sbase + j2;
            v[j2] = (s >= 0 && s < Tt) ? ab[s] : 0.f;
        }
        __syncthreads();                              // prior reads done
#pragma unroll
        for (int it = 0; it < 2; ++it) {
            int r2 = it * 128 + srow;
            async16(WWB + (size_t)r2 * KPAD + k0 + ko, BsDst0 + it * 16384);
        }
        union { short8 s[2]; __hip_bfloat162 hh[8]; } u;
#pragma unroll
        for (int j2 = 0; j2 < 8; ++j2)
            u.hh[j2] = __float22bfloat162_rn(make_float2(v[2 * j2], v[2 * j2 + 1]));
#pragma unroll
        for (int jj = 0; jj < 2; ++jj) {
            int phys = (q4 * 2 + jj) ^ (ar & 7);
            *(short8*)&As[0][ar * 64 + phys * 8] = u.s[jj];
        }
        __syncthreads();
#pragma unroll
        for (int ks = 0; ks < 2; ++ks) {
            short8 af[4], bf[4];
#pragma unroll
            for (int i = 0; i < 4; ++i)
                af[i] = *(const short8*)&As[0][(wr * 64 + i * 16 + m) * 64 + (((ks << 2) + quad) ^ sw) * 8];
#pragma unroll
            for (int j = 0; j < 4; ++j)
                bf[j] = *(const short8*)&Bs[0][(wc * 64 + j * 16 + m) * 64 + (((ks << 2) + quad) ^ sw) * 8];
#pragma unroll
            for (int i = 0; i < 4; ++i)
#pragma unroll
                for (int j = 0; j < 4; ++j)
                    acc[i][j] = __builtin_amdgcn_mfma_f32_16x16x32_bf16(
                        af[i], bf[j], acc[i][j], 0, 0, 0);
        }
    }

    // ---- epilogue: +q+bq, tanh, *g_w, reduce 16 cols/quad, atomicAdd ----------
    const float* qrow = q_buf + (size_t)(h * Bb + b) * DKd;
    const float* bqrow = bq + h * DKd;
    const float* gwrow = g_w + h * DKd;
    float qv[4], gw[4];
#pragma unroll
    for (int j = 0; j < 4; ++j) {
        int e = e0 + wc * 64 + j * 16 + m;
        qv[j] = qrow[e] + bqrow[e];
        gw[j] = gwrow[e];
    }
    float* erow = e_buf + (size_t)(h * Bb + b) * Tt;
#pragma unroll
    for (int i = 0; i < 4; ++i) {
#pragma unroll
        for (int reg = 0; reg < 4; ++reg) {
            float s = 0.f;
#pragma unroll
            for (int j = 0; j < 4; ++j)
                s += fast_tanh(acc[i][j][reg] + qv[j]) * gw[j];
            s += __shfl_xor(s, 1);
            s += __shfl_xor(s, 2);
            s += __shfl_xor(s, 4);
            s += __shfl_xor(s, 8);
            int t = t0 + wr * 64 + i * 16 + quad * 4 + reg;
            if (m == 0 && t < Tt)
                atomicAdd(&erow[t], s);
        }
    }
}

// ---------------- w = softmax(scaling * e) over T ------------------------------
__global__ __launch_bounds__(256) void softmax_kernel(
    const float* __restrict__ e_buf, float* __restrict__ wout)
{
    int rowid = blockIdx.x;
    const float* x = e_buf + rowid * Tt;
    float* y = wout + rowid * Tt;
    int tid = threadIdx.x;
    float v[4];
    float mx = -1e30f;
#pragma unroll
    for (int k = 0; k < 4; ++k) {
        int t = tid + k * 256;
        v[k] = (t < Tt) ? x[t] * SCALING : -1e30f;
        mx = fmaxf(mx, v[k]);
    }
    for (int off = 32; off >= 1; off >>= 1) mx = fmaxf(mx, __shfl_xor(mx, off));
    __shared__ float sm[4];
    __shared__ float ss[4];
    int wave = tid >> 6;
    if ((tid & 63) == 0) sm[wave] = mx;
    __syncthreads();
    mx = fmaxf(fmaxf(sm[0], sm[1]), fmaxf(sm[2], sm[3]));
    float s = 0.f;
#pragma unroll
    for (int k = 0; k < 4; ++k) {
        int t = tid + k * 256;
        v[k] = (t < Tt) ? __expf(v[k] - mx) : 0.f;
        s += v[k];
    }
    for (int off = 32; off >= 1; off >>= 1) s += __shfl_xor(s, off);
    if ((tid & 63) == 0) ss[wave] = s;
    __syncthreads();
    s = ss[0] + ss[1] + ss[2] + ss[3];
    float inv = 1.0f / s;
#pragma unroll
    for (int k = 0; k < 4; ++k) {
        int t = tid + k * 256;
        if (t < Tt) y[t] = v[k] * inv;
    }
}

// ---------------- ctx[h,b,d] += sum_{t in tile} w[h,b,t] * enc16[b,t,d] -------
__global__ __launch_bounds__(256) void ctx_kernel(
    const float* __restrict__ wout, const unsigned short* __restrict__ enc16,
    float* __restrict__ ctx)
{
    int dch = blockIdx.x;    // 0..7 : 128-d chunk
    int b = blockIdx.y;      // 0..31
    int tq = blockIdx.z;     // 0..3 : 250-t chunk
    int t0 = tq * 250;
    int tid = threadIdx.x;
    __shared__ float wl[4][252];
    __shared__ float red[8 * 4 * 128];
    for (int i = tid; i < 1000; i += 256) {
        int h = i / 250, tl = i - h * 250;
        wl[h][tl] = wout[(h * Bb + b) * Tt + t0 + tl];
    }
    __syncthreads();
    int g = tid >> 5, c = tid & 31;
    int d0 = dch * 128;
    float4 a[4];
#pragma unroll
    for (int h = 0; h < 4; ++h) a[h] = make_float4(0.f, 0.f, 0.f, 0.f);
    const unsigned short* encB = enc16 + (size_t)b * TP * EPROJS_ + d0 + c * 4;
    for (int t = t0 + g; t < t0 + 250; t += 8) {
        uint2 raw = *(const uint2*)(encB + (size_t)t * EPROJS_);
        float x0 = __uint_as_float(raw.x << 16);
        float x1 = __uint_as_float(raw.x & 0xffff0000u);
        float x2 = __uint_as_float(raw.y << 16);
        float x3 = __uint_as_float(raw.y & 0xffff0000u);
#pragma unroll
        for (int h = 0; h < 4; ++h) {
            float wv = wl[h][t - t0];
            a[h].x += wv * x0; a[h].y += wv * x1;
            a[h].z += wv * x2; a[h].w += wv * x3;
        }
    }
#pragma unroll
    for (int h = 0; h < 4; ++h)
        *(float4*)&red[((g * 4 + h) << 7) + c * 4] = a[h];
    __syncthreads();
    for (int i = tid; i < 512; i += 256) {
        int h = i >> 7, dd = i & 127;
        float ssum = 0.f;
#pragma unroll
        for (int g2 = 0; g2 < 8; ++g2) ssum += red[((g2 * 4 + h) << 7) + dd];
        atomicAdd(&ctx[(h * Bb + b) * EPROJS_ + d0 + dd], ssum);
    }
}

// ---------------- c[h,b,e] += ctx[h,b,d0:d0+64] . Wv[h,d0:d0+64,e] ------------
__global__ __launch_bounds__(256) void c_kernel(
    const float* __restrict__ ctx, const float* __restrict__ Wv,
    float* __restrict__ c_buf)
{
    int et = blockIdx.x, kc = blockIdx.y, h = blockIdx.z;
    int d0 = kc * 64;
    __shared__ float zs[32][64];
    int tid = threadIdx.x;
    {
        int b = tid >> 3, dc = (tid & 7) * 8;
        const float* p = ctx + ((size_t)(h * Bb + b)) * EPROJS_ + d0 + dc;
        *(float4*)&zs[b][dc] = *(const float4*)p;
        *(float4*)&zs[b][dc + 4] = *(const float4*)(p + 4);
    }
    __syncthreads();
    int e = et * 128 + (tid & 127);
    int dl0 = (tid >> 7) * 32;
    float wv[32];
#pragma unroll
    for (int dl = 0; dl < 32; ++dl)
        wv[dl] = Wv[((size_t)(h * EPROJS_ + d0 + dl0 + dl)) * DVd + e];
#pragma unroll
    for (int b = 0; b < 32; ++b) {
        float s = 0.f;
#pragma unroll
        for (int dl = 0; dl < 32; ++dl) s += zs[b][dl0 + dl] * wv[dl];
        atomicAdd(&c_buf[(h * Bb + b) * DVd + e], s);
    }
}

// ---------------- out[b,o] += c[b,k0:k0+64] . Wo[k0:k0+64,o] ------------------
__global__ __launch_bounds__(256) void out_kernel(
    const float* __restrict__ c_buf, const float* __restrict__ Wo,
    float* __restrict__ outp)
{
    int ot = blockIdx.x;  // 0..7 : 128-o tile
    int kc = blockIdx.y;  // 0..31: 64-k chunk
    int k0 = kc * 64, o0 = ot * 128;
    __shared__ float cs[32][64];
    int tid = threadIdx.x;
    {
        int b = tid >> 3, k8 = (tid & 7) * 8;
        int h = k0 >> 9;
        const float* p = c_buf + ((size_t)(h * Bb + b)) * DVd + (k0 & 511) + k8;
        *(float4*)&cs[b][k8] = *(const float4*)p;
        *(float4*)&cs[b][k8 + 4] = *(const float4*)(p + 4);
    }
    __syncthreads();
    int o = o0 + (tid & 127);
    int kl0 = (tid >> 7) * 32;
    float wo[32];
#pragma unroll
    for (int kl = 0; kl < 32; ++kl)
        wo[kl] = Wo[((size_t)(k0 + kl0 + kl)) * EPROJS_ + o];
#pragma unroll
    for (int b = 0; b < 32; ++b) {
        float s = 0.f;
#pragma unroll
        for (int kl = 0; kl < 32; ++kl) s += cs[b][kl0 + kl] * wo[kl];
        atomicAdd(&outp[b * EPROJS_ + o], s);
    }
}

extern "C" void kernel_launch(void* const* d_in, const int* in_sizes, int n_in,
                              void* d_out, int out_size, void* d_ws, size_t ws_size,
                              hipStream_t stream) {
    const float* enc     = (const float*)d_in[0];
    const float* dec_z   = (const float*)d_in[2];
    const float* att_prev= (const float*)d_in[3];
    const float* Wq      = (const float*)d_in[4];
    const float* bq      = (const float*)d_in[5];
    const float* Wk      = (const float*)d_in[6];
    const float* Wv      = (const float*)d_in[7];
    const float* g_w     = (const float*)d_in[8];
    const float* Watt    = (const float*)d_in[10];
    const float* Wo      = (const float*)d_in[11];
    const float* cw0     = (const float*)d_in[12];
    const float* cw1     = (const float*)d_in[13];
    const float* cw2     = (const float*)d_in[14];
    const float* cw3     = (const float*)d_in[15];

    float* ws    = (float*)d_ws;
    float* q_buf = ws;                          // 65536 f
    float* e_buf = ws + 65536;                  // 128000 f
    float* c_buf = ws + 193536;                 // 65536 f
    float* ctx   = ws + 259072;                 // 131072 f   (zeroed through here)
    unsigned short* enc16 = (unsigned short*)(ws + 390144);   // 32*1024*1024 bf16
    unsigned short* Wkt   = (unsigned short*)(ws + 17167360); // 4*512*1024 bf16
    __hip_bfloat16* WWt   = (__hip_bfloat16*)(ws + 18215936); // 4*512*256 bf16
    float* outp  = (float*)d_out;               // 32768 f
    float* wout  = outp + 32768;                // 128000 f

    // zero atomic-accumulated buffers: q, e, c, ctx, out
    hipMemsetAsync(ws, 0, (size_t)390144 * sizeof(float), stream);
    hipMemsetAsync(d_out, 0, (size_t)32768 * sizeof(float), stream);

    prep_kernel<<<3840, 256, 0, stream>>>(Wk, Wkt, cw0, cw1, cw2, cw3, Watt, WWt,
                                          dec_z, Wq, q_buf, enc, enc16);
    e_kernel<<<1024, 1024, 0, stream>>>(enc16, Wkt, att_prev, WWt,
                                        q_buf, bq, g_w, e_buf);
    softmax_kernel<<<128, 256, 0, stream>>>(e_buf, wout);
    ctx_kernel<<<dim3(8, 32, 4), 256, 0, stream>>>(wout, enc16, ctx);
    c_kernel<<<dim3(4, 16, 4), 256, 0, stream>>>(ctx, Wv, c_buf);
    out_kernel<<<dim3(8, 32), 256, 0, stream>>>(c_buf, Wo, outp);
}